// Round 11
// baseline (371.116 us; speedup 1.0000x reference)
//
#include <hip/hip_runtime.h>
#include <math.h>

#define Bn 32
#define Cn 512
#define Hn 56
#define Wn 56
#define HW (Hn*Wn)           // 3136
#define NPLANE (Bn*Cn)       // 16384
#define F4P (HW/4)           // 784
#define NBLK 2048            // 8 blocks/CU x 256 CU -> all co-resident
#define PPB 8                // planes per block
#define BPB 64               // blocks per batch

typedef float f4 __attribute__((ext_vector_type(4)));

// ---------------------------------------------------------------------------
// Fused persistent kernel, per-batch producer/consumer sync.
// R10 lesson: fusion halves HBM fetch (re-read cache-hits) but MUST keep
// memory-level parallelism: 8 blocks/CU + register prefetch of next plane.
// Block (b,g): pools its 8 contiguous planes (prefetched, 3 barriers/plane,
// 4-lane conv tail) -> s0 -> release-add cnt[b] -> spin (==64) -> FC ->
// rescale its own 8 planes (cache-resident read, nt-store write).
// ---------------------------------------------------------------------------
__global__ __launch_bounds__(256, 8) void fused_kernel(
    const float* __restrict__ x,
    const float* __restrict__ w1,    // [3][3][3]
    const float* __restrict__ w2,    // [3][3]
    const float* __restrict__ fc1,   // [32][512]
    const float* __restrict__ fc2,   // [512][32]
    float* __restrict__ s0,          // [NPLANE] ws
    int*   __restrict__ cnt,         // [Bn] ws, zeroed by memsetAsync
    float* __restrict__ out)
{
    __shared__ float plane[HW];      // 12544 B
    __shared__ float rs[Hn * 4];     // 896 B
    __shared__ float y4[16];
    __shared__ float sv[Cn];         // 2048 B
    __shared__ float hv[32];
    __shared__ float scl[PPB];

    const int bid = blockIdx.x;
    const int t   = threadIdx.x;
    const int b   = bid >> 6;              // batch (64 blocks per batch)
    const int g   = bid & 63;              // 8-plane group within batch
    const int plane0 = b * Cn + g * PPB;

    // hoist tiny weights into wave-0 registers (lanes 0-3 use them)
    float w1r[27], w2r[4];
    if (t < 4) {
        #pragma unroll
        for (int i = 0; i < 27; ++i) w1r[i] = w1[i];
        w2r[0] = w2[4]; w2r[1] = w2[5]; w2r[2] = w2[7]; w2r[3] = w2[8];
    }

    // ---------------- phase 1: pool + conv ----------------
    f4 pf0, pf1, pf2, pf3;
    {
        const f4* px = (const f4*)(x + (size_t)plane0 * HW);
        pf0 = px[t]; pf1 = px[t + 256]; pf2 = px[t + 512];
        if (t < F4P - 768) pf3 = px[t + 768];   // t < 16
    }
    for (int p = 0; p < PPB; ++p) {
        // commit prefetched plane to LDS
        ((f4*)plane)[t]       = pf0;
        ((f4*)plane)[t + 256] = pf1;
        ((f4*)plane)[t + 512] = pf2;
        if (t < F4P - 768) ((f4*)plane)[t + 768] = pf3;
        __syncthreads();                       // (1) plane committed

        // issue prefetch of next plane -- overlaps the reduction below
        if (p + 1 < PPB) {
            const f4* pn = (const f4*)(x + (size_t)(plane0 + p + 1) * HW);
            pf0 = pn[t]; pf1 = pn[t + 256]; pf2 = pn[t + 512];
            if (t < F4P - 768) pf3 = pn[t + 768];
        }

        // 224 threads: thread (h, j) sums plane[h, j*14 .. j*14+13]
        if (t < Hn * 4) {
            const int h = t >> 2, j = t & 3;
            const float* row = plane + h * Wn + j * 14;
            float s = 0.f;
            #pragma unroll
            for (int e = 0; e < 14; ++e) s += row[e];
            rs[h * 4 + j] = s;
        }
        __syncthreads();                       // (2) rs done (plane[] free)

        if (t < 16) {
            const int i = t >> 2, j = t & 3;
            float s = 0.f;
            #pragma unroll
            for (int r = 0; r < 14; ++r) s += rs[(i * 14 + r) * 4 + j];
            y4[i * 4 + j] = s * (1.0f / 196.0f);
        }
        __syncthreads();                       // (3) y4 done (rs[] free)

        // wave-0 lanes 0-3: conv chain, shuffle combine; overlaps next commit
        if (t < 4) {
            const int oy = t >> 1, ox = t & 1;
            float y2[2][2];
            #pragma unroll
            for (int pp = 0; pp < 2; ++pp)
                #pragma unroll
                for (int q = 0; q < 2; ++q)
                    y2[pp][q] = 0.25f * (y4[(2*pp)*4 + 2*q]   + y4[(2*pp)*4 + 2*q+1]
                                       + y4[(2*pp+1)*4 + 2*q] + y4[(2*pp+1)*4 + 2*q+1]);
            const float y1v = 0.25f * (y2[0][0] + y2[0][1] + y2[1][0] + y2[1][1]);

            float acc = 0.f;
            #pragma unroll
            for (int ky = 0; ky < 3; ++ky)
                #pragma unroll
                for (int kx = 0; kx < 3; ++kx) {
                    const int yy = oy + ky, xx = ox + kx;
                    acc += y1v                  * w1r[0*9 + ky*3 + kx];
                    acc += y2[yy >> 1][xx >> 1] * w1r[1*9 + ky*3 + kx];
                    acc += y4[yy*4 + xx]        * w1r[2*9 + ky*3 + kx];
                }
            float v = acc * w2r[t];            // w2[1+oy][1+ox]
            v += __shfl_xor(v, 1);
            v += __shfl_xor(v, 2);
            if (t == 0)
                __hip_atomic_store(&s0[plane0 + p], v,
                                   __ATOMIC_RELAXED, __HIP_MEMORY_SCOPE_AGENT);
        }
        // no barrier: y4[] next written after barrier (2) of next iter,
        // and wave0 rejoins at barrier (1) after the conv.
    }

    // ---------------- batch-level sync ----------------
    __syncthreads();                           // conv of last plane done
    if (t == 0) {
        __hip_atomic_fetch_add(&cnt[b], 1,
                               __ATOMIC_RELEASE, __HIP_MEMORY_SCOPE_AGENT);
        while (__hip_atomic_load(&cnt[b],
                                 __ATOMIC_ACQUIRE, __HIP_MEMORY_SCOPE_AGENT) < BPB)
            __builtin_amdgcn_s_sleep(16);
    }
    __syncthreads();

    // ---------------- phase 2: FC + scale ----------------
    for (int c = t; c < Cn; c += 256) sv[c] = s0[b * Cn + c];
    __syncthreads();

    {
        const int r = t >> 3, l8 = t & 7;
        float acc = 0.f;
        for (int c = l8; c < Cn; c += 8) acc += sv[c] * fc1[r * Cn + c];
        acc += __shfl_xor(acc, 1);
        acc += __shfl_xor(acc, 2);
        acc += __shfl_xor(acc, 4);
        if (l8 == 0) hv[r] = fmaxf(acc, 0.f);
    }
    __syncthreads();

    if (t < PPB) {
        const int c = g * PPB + t;
        float acc = 0.f;
        #pragma unroll
        for (int r = 0; r < 32; ++r) acc += hv[r] * fc2[c * 32 + r];
        scl[t] = 1.0f / (1.0f + expf(-acc));
    }
    __syncthreads();

    for (int p = 0; p < PPB; ++p) {
        const float sc = scl[p];
        const f4* px = (const f4*)x   + (size_t)(plane0 + p) * F4P;
        f4*       po = (f4*)out      + (size_t)(plane0 + p) * F4P;
        for (int f = t; f < F4P; f += 256) {
            f4 v = px[f];
            v *= sc;
            __builtin_nontemporal_store(v, po + f);
        }
    }
}

extern "C" void kernel_launch(void* const* d_in, const int* in_sizes, int n_in,
                              void* d_out, int out_size, void* d_ws, size_t ws_size,
                              hipStream_t stream) {
    const float* x   = (const float*)d_in[0];
    const float* w1  = (const float*)d_in[1];
    const float* w2  = (const float*)d_in[2];
    const float* fc1 = (const float*)d_in[3];
    const float* fc2 = (const float*)d_in[4];
    float* out = (float*)d_out;

    float* s0  = (float*)d_ws;               // [NPLANE]
    int*   cnt = (int*)(s0 + NPLANE);        // [Bn]

    hipMemsetAsync(cnt, 0, Bn * sizeof(int), stream);
    fused_kernel<<<NBLK, 256, 0, stream>>>(x, w1, w2, fc1, fc2, s0, cnt, out);
}

// Round 12
// 109.870 us; speedup vs baseline: 3.3778x; 3.3778x over previous
//
#include <hip/hip_runtime.h>
#include <math.h>

#define Bn 32
#define Cn 512
#define Hn 56
#define Wn 56
#define HW (Hn*Wn)           // 3136
#define NPLANE (Bn*Cn)       // 16384
#define F4P (HW/4)           // 784
#define PPB 16               // planes per scale-block

typedef float f4 __attribute__((ext_vector_type(4)));

// ---------------------------------------------------------------------------
// Kernel A: per-(b,c) multi-scale pooling + conv chain -> scalar s0[bc]
// R4-exact (known-good 108 us structure). One block per plane.
// ---------------------------------------------------------------------------
__global__ __launch_bounds__(256) void pool_conv_kernel(
    const float* __restrict__ x,
    const float* __restrict__ w1,   // [3][3][3] (ic,ky,kx)
    const float* __restrict__ w2,   // [3][3]
    float* __restrict__ s0)         // [NPLANE]
{
    __shared__ float plane[HW];     // 12544 B
    __shared__ float rs[Hn * 4];
    __shared__ float y4[16];

    const int bc = blockIdx.x;
    const int t  = threadIdx.x;
    const float* src = x + (size_t)bc * HW;

    for (int f = t; f < F4P; f += 256)
        ((f4*)plane)[f] = ((const f4*)src)[f];
    __syncthreads();

    if (t < Hn * 4) {
        const int h = t >> 2, j = t & 3;
        const float* row = plane + h * Wn + j * 14;
        float s = 0.f;
        #pragma unroll
        for (int e = 0; e < 14; ++e) s += row[e];
        rs[h * 4 + j] = s;
    }
    __syncthreads();

    if (t < 16) {
        const int i = t >> 2, j = t & 3;
        float s = 0.f;
        #pragma unroll
        for (int r = 0; r < 14; ++r) s += rs[(i * 14 + r) * 4 + j];
        y4[i * 4 + j] = s * (1.0f / 196.0f);
    }
    __syncthreads();

    if (t == 0) {
        float y2[2][2];
        #pragma unroll
        for (int p = 0; p < 2; ++p)
            #pragma unroll
            for (int q = 0; q < 2; ++q)
                y2[p][q] = 0.25f * (y4[(2*p)*4 + 2*q]   + y4[(2*p)*4 + 2*q+1]
                                  + y4[(2*p+1)*4 + 2*q] + y4[(2*p+1)*4 + 2*q+1]);
        const float y1 = 0.25f * (y2[0][0] + y2[0][1] + y2[1][0] + y2[1][1]);

        float z[2][2];
        #pragma unroll
        for (int oy = 0; oy < 2; ++oy)
            #pragma unroll
            for (int ox = 0; ox < 2; ++ox) {
                float acc = 0.f;
                #pragma unroll
                for (int ky = 0; ky < 3; ++ky)
                    #pragma unroll
                    for (int kx = 0; kx < 3; ++kx) {
                        const int yy = oy + ky, xx = ox + kx;
                        acc += y1                   * w1[0*9 + ky*3 + kx];
                        acc += y2[yy >> 1][xx >> 1] * w1[1*9 + ky*3 + kx];
                        acc += y4[yy*4 + xx]        * w1[2*9 + ky*3 + kx];
                    }
                z[oy][ox] = acc;
            }

        s0[bc] = z[0][0] * w2[1*3+1] + z[0][1] * w2[1*3+2]
               + z[1][0] * w2[2*3+1] + z[1][1] * w2[2*3+2];
    }
}

// ---------------------------------------------------------------------------
// Kernel B (fused FC + scale): 1024 blocks x 16 planes. Block (b,g)
// recomputes the tiny per-batch FC (halved redundancy vs 2048-block version)
// and rescales its 16 contiguous planes. nt-LOADS for x (dying stream,
// mostly HBM misses -> don't allocate in cache); nt-STORES for out.
// Inner loop kept in the simple R4 shape the compiler schedules well.
// ---------------------------------------------------------------------------
__global__ __launch_bounds__(256) void fc_scale_kernel(
    const float* __restrict__ x,
    const float* __restrict__ s0,    // [NPLANE]
    const float* __restrict__ fc1,   // [32][512]
    const float* __restrict__ fc2,   // [512][32]
    float* __restrict__ out)
{
    __shared__ float sv[Cn];
    __shared__ float hv[32];
    __shared__ float scl[PPB];

    const int b = blockIdx.x >> 5;   // batch (32 blocks per batch)
    const int g = blockIdx.x & 31;   // 16-plane group within batch
    const int t = threadIdx.x;

    for (int c = t; c < Cn; c += 256) sv[c] = s0[b * Cn + c];
    __syncthreads();

    // h[r] = relu(sum_c sv[c] * fc1[r][c]); 8 lanes per row
    {
        const int r = t >> 3, l8 = t & 7;
        float acc = 0.f;
        for (int c = l8; c < Cn; c += 8) acc += sv[c] * fc1[r * Cn + c];
        acc += __shfl_xor(acc, 1);
        acc += __shfl_xor(acc, 2);
        acc += __shfl_xor(acc, 4);
        if (l8 == 0) hv[r] = fmaxf(acc, 0.f);
    }
    __syncthreads();

    // scl[p] = sigmoid(hv . fc2[g*16+p]) for this block's 16 channels
    if (t < PPB) {
        const int c = g * PPB + t;
        float acc = 0.f;
        #pragma unroll
        for (int r = 0; r < 32; ++r) acc += hv[r] * fc2[c * 32 + r];
        scl[t] = 1.0f / (1.0f + expf(-acc));
    }
    __syncthreads();

    // scale 16 planes: nt-load x, nt-store out
    for (int p = 0; p < PPB; ++p) {
        const int plane = b * Cn + g * PPB + p;
        const float sc = scl[p];
        const f4* px = (const f4*)x   + (size_t)plane * F4P;
        f4*       po = (f4*)out      + (size_t)plane * F4P;
        for (int f = t; f < F4P; f += 256) {
            f4 v = __builtin_nontemporal_load(px + f);
            v *= sc;
            __builtin_nontemporal_store(v, po + f);
        }
    }
}

extern "C" void kernel_launch(void* const* d_in, const int* in_sizes, int n_in,
                              void* d_out, int out_size, void* d_ws, size_t ws_size,
                              hipStream_t stream) {
    const float* x   = (const float*)d_in[0];
    const float* w1  = (const float*)d_in[1];
    const float* w2  = (const float*)d_in[2];
    const float* fc1 = (const float*)d_in[3];
    const float* fc2 = (const float*)d_in[4];
    float* out = (float*)d_out;
    float* s0  = (float*)d_ws;          // [NPLANE]

    pool_conv_kernel<<<NPLANE, 256, 0, stream>>>(x, w1, w2, s0);
    fc_scale_kernel<<<NPLANE / PPB, 256, 0, stream>>>(x, s0, fc1, fc2, out);
}